// Round 5
// baseline (614.233 us; speedup 1.0000x reference)
//
#include <hip/hip_runtime.h>
#include <math.h>

#define DEPTH 18
#define NINT ((1 << (DEPTH - 1)) - 1)   // internal nodes (h/c stored)
#define NVOCAB 50000

typedef unsigned short bf16raw;
typedef __bf16 bf16x8 __attribute__((ext_vector_type(8)));
typedef float f32x4 __attribute__((ext_vector_type(4)));
typedef short short8 __attribute__((ext_vector_type(8)));

__device__ __forceinline__ float sigm(float x) { return 1.0f / (1.0f + __expf(-x)); }

__device__ __forceinline__ float bf2f(bf16raw u) {
    union { unsigned int i; float f; } v;
    v.i = ((unsigned int)u) << 16;
    return v.f;
}
__device__ __forceinline__ bf16raw f2bf(float f) {
    union { float f; unsigned int i; } v;
    v.f = f;
    unsigned int r = v.i + 0x7FFFu + ((v.i >> 16) & 1u);  // RNE
    return (bf16raw)(r >> 16);
}

// ---------------------------------------------------------------------------
__global__ __launch_bounds__(256) void k_prep_embeds(const float* __restrict__ src,
                                                     bf16raw* __restrict__ dst, int n4)
{
    int i = blockIdx.x * blockDim.x + threadIdx.x;
    if (i < n4) {
        float4 v = ((const float4*)src)[i];
        ushort4 o;
        o.x = f2bf(v.x); o.y = f2bf(v.y); o.z = f2bf(v.z); o.w = f2bf(v.w);
        ((ushort4*)dst)[i] = o;
    }
}

// ---------------------------------------------------------------------------
// Bfrag: fragment-linear B.  Gate order: 0=i, 1=u, 2=o, 3=f1, 4=f2.
// Physical: Bfrag[((tile*12 + ktile)*64 + lane)*8 + e] where tile=col>>4,
// lane = ((k>>3)&3)*16 + (col&15), ktile=k>>5, e=k&7.  A wave loading one
// MFMA B fragment reads 64 consecutive 16B chunks -> one coalesced 1KB txn.
// f1 zero for k>=256, f2 zero for k in [128,256).
// ---------------------------------------------------------------------------
__global__ __launch_bounds__(128) void k_prep_bcat(
    const float* __restrict__ Wix, const float* __restrict__ bix,
    const float* __restrict__ Wih, const float* __restrict__ bih,
    const float* __restrict__ Wfx, const float* __restrict__ bfx,
    const float* __restrict__ Wfh, const float* __restrict__ bfh,
    const float* __restrict__ Wox, const float* __restrict__ box_,
    const float* __restrict__ Woh, const float* __restrict__ boh,
    const float* __restrict__ Wux, const float* __restrict__ bux,
    const float* __restrict__ Wuh, const float* __restrict__ buh,
    bf16raw* __restrict__ Bfrag, float* __restrict__ bias_cat)
{
    const int j = blockIdx.x;        // 0..639
    const int grp = j >> 7, jj = j & 127;
    const float *Wx, *Wh, *bx, *bh;
    switch (grp) {
        case 0: Wx = Wix; Wh = Wih; bx = bix;  bh = bih; break;
        case 1: Wx = Wux; Wh = Wuh; bx = bux;  bh = buh; break;
        case 2: Wx = Wox; Wh = Woh; bx = box_; bh = boh; break;
        default: Wx = Wfx; Wh = Wfh; bx = bfx; bh = bfh; break;
    }
    const int tile = j >> 4, lr = j & 15;
    for (int k = threadIdx.x; k < 384; k += blockDim.x) {
        float v;
        if (k < 128) {
            v = Wx[jj * 128 + k];
        } else if (k < 256) {
            v = (grp == 4) ? 0.f : Wh[jj * 128 + (k - 128)];
        } else {
            v = (grp == 3) ? 0.f : Wh[jj * 128 + (k - 256)];
        }
        const int idx = ((tile * 12 + (k >> 5)) * 64 + ((k >> 3) & 3) * 16 + lr) * 8 + (k & 7);
        Bfrag[idx] = f2bf(v);
    }
    if (threadIdx.x == 0) bias_cat[j] = bx[jj] + bh[jj];
}

// ---------------------------------------------------------------------------
// Pipelined fragment helpers (all indices compile-time -> stay in registers).
// ---------------------------------------------------------------------------
__device__ __forceinline__ constexpr unsigned chunk_mask(int kt) {
    return (kt < 4) ? 0x1Fu : (kt < 8 ? 0x0Fu : 0x17u);
}

template<int KT>
__device__ __forceinline__ void lv_load(const bf16raw* __restrict__ bfbase, int w,
                                        bf16x8 (&buf)[10])
{
    constexpr unsigned mask = chunk_mask(KT);
    int s = 0;
#pragma unroll
    for (int g = 0; g < 5; ++g) {
        if (!((mask >> g) & 1)) continue;
#pragma unroll
        for (int jj = 0; jj < 2; ++jj) {
            buf[s] = *(const bf16x8*)(bfbase + (long)(((g * 8 + w * 2 + jj) * 12 + KT) * 512));
            ++s;
        }
    }
}

template<int KT>
__device__ __forceinline__ void lv_mfma(const bf16raw* __restrict__ sA, int lrow, int lquad,
                                        bf16x8 (&buf)[10], f32x4 (&acc)[5][2][2])
{
    bf16x8 af[2];
#pragma unroll
    for (int i = 0; i < 2; ++i)
        af[i] = *(const bf16x8*)&sA[(i * 16 + lrow) * 392 + KT * 32 + lquad * 8];
    constexpr unsigned mask = chunk_mask(KT);
    int s = 0;
#pragma unroll
    for (int g = 0; g < 5; ++g) {
        if (!((mask >> g) & 1)) continue;
#pragma unroll
        for (int jj = 0; jj < 2; ++jj) {
#pragma unroll
            for (int i = 0; i < 2; ++i)
                acc[g][i][jj] = __builtin_amdgcn_mfma_f32_16x16x32_bf16(af[i], buf[s], acc[g][i][jj], 0, 0, 0);
            ++s;
        }
    }
}

template<int CB, int KT>
__device__ __forceinline__ void lp_load(const bf16raw* __restrict__ bfbase, int wcol,
                                        bf16x8 (&buf)[4])
{
#pragma unroll
    for (int j = 0; j < 4; ++j)
        buf[j] = *(const bf16x8*)(bfbase + (long)(((CB * 8 + (wcol >> 4) + j) * 12 + KT) * 512));
}

template<int KT>
__device__ __forceinline__ void lp_mfma(const bf16raw* __restrict__ sA, int wrow, int lrow,
                                        int lquad, bf16x8 (&buf)[4], f32x4 (&acc)[4][4])
{
    bf16x8 af[4];
#pragma unroll
    for (int i = 0; i < 4; ++i)
        af[i] = *(const bf16x8*)&sA[(wrow + i * 16 + lrow) * 136 + KT * 32 + lquad * 8];
#pragma unroll
    for (int i = 0; i < 4; ++i)
#pragma unroll
        for (int j = 0; j < 4; ++j)
            acc[i][j] = __builtin_amdgcn_mfma_f32_16x16x32_bf16(af[i], buf[j], acc[i][j], 0, 0, 0);
}

// ---------------------------------------------------------------------------
// k_leafpre: per-vocab leaf tables. hc_leaf[v][0..127]=h, [128..255]=c;
// lossv6[v][0..4]=logits, [5]=lse.  A staged once in LDS; B via pipelined
// coalesced Bfrag loads (depth-1, 2 buffers); barrier-free K-loop.
// ---------------------------------------------------------------------------
__global__ __launch_bounds__(256, 2) void k_leafpre(
    const bf16raw* __restrict__ embeds_bf,
    const bf16raw* __restrict__ Bfrag, const float* __restrict__ bias_cat,
    const float* __restrict__ Wout, const float* __restrict__ bout,
    bf16raw* __restrict__ hc_leaf, float* __restrict__ lossv6, int vbase, int nv)
{
    vbase += blockIdx.x * 128;
    nv -= vbase;
    if (nv > 128) nv = 128;
    if (nv <= 0) return;

    __shared__ __align__(16) bf16raw sA[128 * 136];
    __shared__ __align__(16) bf16raw sT[128 * 136];
    __shared__ float sWout[5 * 128];

    const int t = threadIdx.x;
    for (int i = t; i < 640; i += 256) sWout[i] = Wout[i];

    // ---- stage full A tile once: 2 threads/row x 8 short8 ----
    {
        const int row = t >> 1;
        const int half = (t & 1) * 64;
        const int arow = (row < nv) ? row : 0;
        const bf16raw* ax = embeds_bf + (long)(vbase + arow) * 128;
#pragma unroll
        for (int s = 0; s < 8; ++s)
            *(short8*)&sA[row * 136 + half + s * 8] = *(const short8*)(ax + half + s * 8);
    }

    const int lane = t & 63;
    const int w = t >> 6;
    const int wrow = (w >> 1) * 64;
    const int wcol = (w & 1) * 64;
    const int lrow = lane & 15;
    const int lquad = lane >> 4;

    __syncthreads();

    const bf16raw* bfbase = Bfrag + (long)lane * 8;

    float tval[4][4][4];
    f32x4 acc[4][4];
    bf16x8 c0[4], c1[4];

#define LP_RUNGEMM(CB)                                                     \
    {                                                                      \
        _Pragma("unroll")                                                  \
        for (int i = 0; i < 4; i++)                                        \
            _Pragma("unroll")                                              \
            for (int j = 0; j < 4; j++) acc[i][j] = (f32x4){0.f,0.f,0.f,0.f}; \
        lp_load<CB,0>(bfbase, wcol, c0);                                   \
        lp_load<CB,1>(bfbase, wcol, c1);                                   \
        lp_mfma<0>(sA, wrow, lrow, lquad, c0, acc);                        \
        lp_load<CB,2>(bfbase, wcol, c0);                                   \
        lp_mfma<1>(sA, wrow, lrow, lquad, c1, acc);                        \
        lp_load<CB,3>(bfbase, wcol, c1);                                   \
        lp_mfma<2>(sA, wrow, lrow, lquad, c0, acc);                        \
        lp_mfma<3>(sA, wrow, lrow, lquad, c1, acc);                        \
    }

    // ---- i gate ----
    LP_RUNGEMM(0);
#pragma unroll
    for (int i = 0; i < 4; i++)
#pragma unroll
        for (int jj = 0; jj < 4; jj++) {
            const float b = bias_cat[wcol + jj * 16 + lrow];
#pragma unroll
            for (int r = 0; r < 4; r++) tval[i][jj][r] = sigm(acc[i][jj][r] + b);
        }
    // ---- u gate: tval = c = i*u ----
    LP_RUNGEMM(1);
#pragma unroll
    for (int i = 0; i < 4; i++)
#pragma unroll
        for (int jj = 0; jj < 4; jj++) {
            const float b = bias_cat[128 + wcol + jj * 16 + lrow];
#pragma unroll
            for (int r = 0; r < 4; r++) tval[i][jj][r] *= tanhf(acc[i][jj][r] + b);
        }
    // write c tile, then keep tanh(c) in regs
#pragma unroll
    for (int i = 0; i < 4; i++)
#pragma unroll
        for (int jj = 0; jj < 4; jj++)
#pragma unroll
            for (int r = 0; r < 4; r++) {
                const int m = wrow + i * 16 + lquad * 4 + r;
                const int j = wcol + jj * 16 + lrow;
                sT[m * 136 + j] = f2bf(tval[i][jj][r]);
            }
#pragma unroll
    for (int i = 0; i < 4; i++)
#pragma unroll
        for (int jj = 0; jj < 4; jj++)
#pragma unroll
            for (int r = 0; r < 4; r++) tval[i][jj][r] = tanhf(tval[i][jj][r]);
    __syncthreads();
    // flush c to hc_leaf[.., 128..255]
#pragma unroll
    for (int s = 0; s < 8; ++s) {
        int ci = t + 256 * s;
        int row = ci >> 4, c8 = (ci & 15) * 8;
        if (row < nv)
            *(short8*)(hc_leaf + (long)(vbase + row) * 256 + 128 + c8) = *(const short8*)&sT[row * 136 + c8];
    }
    // ---- o gate: h = sigm(o) * tanh(c) ----
    LP_RUNGEMM(2);
    __syncthreads();
#pragma unroll
    for (int i = 0; i < 4; i++)
#pragma unroll
        for (int jj = 0; jj < 4; jj++) {
            const float b = bias_cat[256 + wcol + jj * 16 + lrow];
#pragma unroll
            for (int r = 0; r < 4; r++) {
                const int m = wrow + i * 16 + lquad * 4 + r;
                const int j = wcol + jj * 16 + lrow;
                sT[m * 136 + j] = f2bf(sigm(acc[i][jj][r] + b) * tval[i][jj][r]);
            }
        }
    __syncthreads();
    // flush h to hc_leaf[.., 0..127]
#pragma unroll
    for (int s = 0; s < 8; ++s) {
        int ci = t + 256 * s;
        int row = ci >> 4, c8 = (ci & 15) * 8;
        if (row < nv)
            *(short8*)(hc_leaf + (long)(vbase + row) * 256 + c8) = *(const short8*)&sT[row * 136 + c8];
    }
    // logits + lse per vocab row
    {
        const int row = t >> 1, half = t & 1;
        float p[5] = {0.f, 0.f, 0.f, 0.f, 0.f};
        for (int k = 0; k < 64; ++k) {
            float hv = bf2f(sT[row * 136 + half * 64 + k]);
#pragma unroll
            for (int l = 0; l < 5; l++) p[l] += hv * sWout[l * 128 + half * 64 + k];
        }
#pragma unroll
        for (int l = 0; l < 5; l++) p[l] += __shfl_down(p[l], 1);
        if (half == 0 && row < nv) {
            float lg[5], mx = -1e30f;
#pragma unroll
            for (int l = 0; l < 5; l++) {
                lg[l] = p[l] + bout[l];
                mx = fmaxf(mx, lg[l]);
            }
            float se = 0.f;
#pragma unroll
            for (int l = 0; l < 5; l++) se += __expf(lg[l] - mx);
            float lse = __logf(se) + mx;
            float* dst = lossv6 + (long)(vbase + row) * 6;
#pragma unroll
            for (int l = 0; l < 5; l++) dst[l] = lg[l];
            dst[5] = lse;
        }
    }
#undef LP_RUNGEMM
}

// ---------------------------------------------------------------------------
// k_level32: fused level kernel (5-gate GEMM + gate math + h/c + loss).
//  - block = 32 nodes, 256 threads (4 waves).
//  - A tile staged once in LDS; children c staged in LDS; one barrier, then
//    the whole 5-gate K-loop is barrier-free.
//  - B via pipelined coalesced Bfrag loads: 3-buffer depth-2 rotation issues
//    chunk k+2's 8-10 fragment loads before chunk k's MFMAs, hiding the
//    ~250cy L2 latency that round-4's serial load->MFMA chain exposed
//    (MfmaUtil 9.6%, VGPR 80 -> compiler kept nothing in flight).
//  - launch_bounds (256,2): depth-2 pipeline needs ~200+ unified regs; a
//    3-block/CU cap (<=170) would force spills.
// ---------------------------------------------------------------------------
__global__ __launch_bounds__(256, 2) void k_level32(
    const bf16raw* __restrict__ embeds_bf, const int* __restrict__ words,
    const int* __restrict__ labels,
    bf16raw* __restrict__ h_all, bf16raw* __restrict__ c_all,
    const bf16raw* __restrict__ hc_leaf, const float* __restrict__ lossv6,
    const bf16raw* __restrict__ Bfrag, const float* __restrict__ bias_cat,
    const float* __restrict__ Wout, const float* __restrict__ bout,
    float* __restrict__ partials, float* __restrict__ out,
    int off, int nm, int leafkids, int isroot)
{
    __shared__ __align__(16) bf16raw sA[32 * 392];    // A tile, row stride 392
    __shared__ __align__(16) bf16raw sCT[64 * 136];   // children c; reused as c/h out tiles
    __shared__ float sWout[640];

    const int t = threadIdx.x;
    const int m0 = blockIdx.x * 32;

    for (int i = t; i < 640; i += 256) sWout[i] = Wout[i];

    // ---- stage A tile: 8 threads per row; each thread 6 short8 (full cover) ----
    {
        const int row = t >> 3;            // 0..31
        const int co = (t & 7) * 8;        // 0..56, 16B chunks
        int mm = m0 + row; if (mm >= nm) mm = nm - 1;
        const long g = (long)off + mm;
        const bf16raw* px = embeds_bf + (long)words[g] * 128;
        const bf16raw *p1, *p2;
        if (leafkids) {
            p1 = hc_leaf + (long)words[2 * g + 1] * 256;
            p2 = hc_leaf + (long)words[2 * g + 2] * 256;
        } else {
            p1 = h_all + (2 * g + 1) * 128;
            p2 = h_all + (2 * g + 2) * 128;
        }
        *(short8*)&sA[row * 392 + co]            = *(const short8*)(px + co);
        *(short8*)&sA[row * 392 + 64 + co]       = *(const short8*)(px + 64 + co);
        *(short8*)&sA[row * 392 + 128 + co]      = *(const short8*)(p1 + co);
        *(short8*)&sA[row * 392 + 192 + co]      = *(const short8*)(p1 + 64 + co);
        *(short8*)&sA[row * 392 + 256 + co]      = *(const short8*)(p2 + co);
        *(short8*)&sA[row * 392 + 320 + co]      = *(const short8*)(p2 + 64 + co);
    }
    // ---- stage children c: slot = 2*mlocal + childIdx; 4 thr/slot x 4 short8 ----
    {
        const int slot = t >> 2;           // 0..63
        const int cc = (t & 3) * 8;        // 0..24
        int mm = m0 + (slot >> 1); if (mm >= nm) mm = nm - 1;
        const long g = (long)off + mm;
        const long cg = 2 * g + 1 + (slot & 1);
        const bf16raw* pc = leafkids ? (hc_leaf + (long)words[cg] * 256 + 128)
                                     : (c_all + cg * 128);
#pragma unroll
        for (int s = 0; s < 4; ++s)
            *(short8*)&sCT[slot * 136 + s * 32 + cc] = *(const short8*)(pc + s * 32 + cc);
    }

    const int lane = t & 63;
    const int w = t >> 6;
    const int lrow = lane & 15;
    const int lquad = lane >> 4;

    __syncthreads();   // A tile, children, sWout staged

    // ---- 5-gate GEMM, barrier-free, pipelined coalesced B ----
    f32x4 acc[5][2][2];
#pragma unroll
    for (int g = 0; g < 5; ++g)
#pragma unroll
        for (int i = 0; i < 2; ++i)
#pragma unroll
            for (int jj = 0; jj < 2; ++jj) acc[g][i][jj] = (f32x4){0.f, 0.f, 0.f, 0.f};

    const bf16raw* bfbase = Bfrag + (long)lane * 8;

    bf16x8 b0[10], b1[10], b2[10];
    lv_load<0>(bfbase, w, b0);
    lv_load<1>(bfbase, w, b1);
    lv_load<2>(bfbase, w, b2);  lv_mfma<0>(sA, lrow, lquad, b0, acc);
    lv_load<3>(bfbase, w, b0);  lv_mfma<1>(sA, lrow, lquad, b1, acc);
    lv_load<4>(bfbase, w, b1);  lv_mfma<2>(sA, lrow, lquad, b2, acc);
    lv_load<5>(bfbase, w, b2);  lv_mfma<3>(sA, lrow, lquad, b0, acc);
    lv_load<6>(bfbase, w, b0);  lv_mfma<4>(sA, lrow, lquad, b1, acc);
    lv_load<7>(bfbase, w, b1);  lv_mfma<5>(sA, lrow, lquad, b2, acc);
    lv_load<8>(bfbase, w, b2);  lv_mfma<6>(sA, lrow, lquad, b0, acc);
    lv_load<9>(bfbase, w, b0);  lv_mfma<7>(sA, lrow, lquad, b1, acc);
    lv_load<10>(bfbase, w, b1); lv_mfma<8>(sA, lrow, lquad, b2, acc);
    lv_load<11>(bfbase, w, b2); lv_mfma<9>(sA, lrow, lquad, b0, acc);
                                lv_mfma<10>(sA, lrow, lquad, b1, acc);
                                lv_mfma<11>(sA, lrow, lquad, b2, acc);

    // ---- gate math fully in-register (reads children from sCT) ----
    float cv[2][2][4], hv[2][2][4];
#pragma unroll
    for (int i = 0; i < 2; ++i)
#pragma unroll
        for (int jj = 0; jj < 2; ++jj) {
            const int j = w * 32 + jj * 16 + lrow;
            const float bi = bias_cat[j];
            const float bu = bias_cat[128 + j];
            const float bo = bias_cat[256 + j];
            const float b1v = bias_cat[384 + j];
            const float b2v = bias_cat[512 + j];
#pragma unroll
            for (int r = 0; r < 4; ++r) {
                const int m = i * 16 + lquad * 4 + r;
                const float c1 = bf2f(sCT[(2 * m) * 136 + j]);
                const float c2 = bf2f(sCT[(2 * m + 1) * 136 + j]);
                const float iv = sigm(acc[0][i][jj][r] + bi);
                const float uv = tanhf(acc[1][i][jj][r] + bu);
                const float ov = sigm(acc[2][i][jj][r] + bo);
                const float f1 = sigm(acc[3][i][jj][r] + b1v);
                const float f2 = sigm(acc[4][i][jj][r] + b2v);
                const float c = iv * uv + f1 * c1 + f2 * c2;
                cv[i][jj][r] = c;
                hv[i][jj][r] = ov * tanhf(c);
            }
        }
    __syncthreads();   // all child reads complete before overwriting sCT

    // ---- write c (rows 0..31) and h (rows 32..63) tiles ----
#pragma unroll
    for (int i = 0; i < 2; ++i)
#pragma unroll
        for (int jj = 0; jj < 2; ++jj) {
            const int j = w * 32 + jj * 16 + lrow;
#pragma unroll
            for (int r = 0; r < 4; ++r) {
                const int m = i * 16 + lquad * 4 + r;
                sCT[m * 136 + j] = f2bf(cv[i][jj][r]);
                sCT[(32 + m) * 136 + j] = f2bf(hv[i][jj][r]);
            }
        }
    __syncthreads();

    // ---- coalesced flush: rows 0..31 -> c_all, rows 32..63 -> h_all ----
#pragma unroll
    for (int q = 0; q < 4; ++q) {
        int ci = t + 256 * q;               // 0..1023
        int row = ci >> 4;                  // 0..63
        int c8 = (ci & 15) * 8;
        int m = row & 31;
        if (m0 + m < nm) {
            bf16raw* dst = (row < 32) ? c_all : h_all;
            *(short8*)(dst + ((long)off + m0 + m) * 128 + c8) = *(const short8*)&sCT[row * 136 + c8];
        }
    }

    // ---- logits + loss: 8 threads per node ----
    {
        const int row = t >> 3, oct = t & 7;
        float p[5] = {0.f, 0.f, 0.f, 0.f, 0.f};
#pragma unroll
        for (int k0 = 0; k0 < 16; ++k0) {
            const int k = oct * 16 + k0;
            float hval = bf2f(sCT[(32 + row) * 136 + k]);
#pragma unroll
            for (int l = 0; l < 5; l++) p[l] += hval * sWout[l * 128 + k];
        }
#pragma unroll
        for (int l = 0; l < 5; l++) {
            p[l] += __shfl_down(p[l], 4);
            p[l] += __shfl_down(p[l], 2);
            p[l] += __shfl_down(p[l], 1);
        }
        if (oct == 0 && m0 + row < nm) {
            const long g = (long)off + m0 + row;
            float lg[5], mx = -1e30f;
#pragma unroll
            for (int l = 0; l < 5; l++) {
                lg[l] = p[l] + bout[l];
                mx = fmaxf(mx, lg[l]);
            }
            float se = 0.f;
#pragma unroll
            for (int l = 0; l < 5; l++) se += __expf(lg[l] - mx);
            float lse = __logf(se) + mx;
            float lossNode = lse - lg[labels[g]];
            if (leafkids) {
                const float* lv1 = lossv6 + (long)words[2 * g + 1] * 6;
                const float* lv2 = lossv6 + (long)words[2 * g + 2] * 6;
                lossNode += (lv1[5] - lv1[labels[2 * g + 1]])
                          + (lv2[5] - lv2[labels[2 * g + 2]]);
            }
            atomicAdd(&partials[(int)(g & 1023)], lossNode);
            if (isroot) {
#pragma unroll
                for (int l = 0; l < 5; l++) out[l] = lg[l] - lse;
            }
        }
    }
}

__global__ __launch_bounds__(256) void k3_reduce(const float* __restrict__ partials,
                                                 float* __restrict__ out)
{
    const int t = threadIdx.x;
    float s = 0.f;
    for (int i = t; i < 1024; i += 256) s += partials[i];
#pragma unroll
    for (int d = 32; d > 0; d >>= 1) s += __shfl_down(s, d);
    __shared__ float red[4];
    if ((t & 63) == 0) red[t >> 6] = s;
    __syncthreads();
    if (t == 0) out[5] = red[0] + red[1] + red[2] + red[3];
}

// ---------------------------------------------------------------------------
extern "C" void kernel_launch(void* const* d_in, const int* in_sizes, int n_in,
                              void* d_out, int out_size, void* d_ws, size_t ws_size,
                              hipStream_t stream)
{
    const float* embeds = (const float*)d_in[0];
    const int* words = (const int*)d_in[1];
    const int* labels = (const int*)d_in[2];
    const float* Wix = (const float*)d_in[5],  *bix  = (const float*)d_in[6];
    const float* Wih = (const float*)d_in[7],  *bih  = (const float*)d_in[8];
    const float* Wfx = (const float*)d_in[9],  *bfx  = (const float*)d_in[10];
    const float* Wfh = (const float*)d_in[11], *bfh  = (const float*)d_in[12];
    const float* Wox = (const float*)d_in[13], *box_ = (const float*)d_in[14];
    const float* Woh = (const float*)d_in[15], *boh  = (const float*)d_in[16];
    const float* Wux = (const float*)d_in[17], *bux  = (const float*)d_in[18];
    const float* Wuh = (const float*)d_in[19], *buh  = (const float*)d_in[20];
    const float* Wout = (const float*)d_in[21], *bout = (const float*)d_in[22];
    float* out = (float*)d_out;

    char* ws = (char*)d_ws;
    const size_t treeElems = (size_t)NINT * 128;
    bf16raw* h_all = (bf16raw*)ws;
    bf16raw* c_all = h_all + treeElems;
    bf16raw* embeds_bf = c_all + treeElems;
    bf16raw* Bfrag = embeds_bf + (size_t)NVOCAB * 128;
    bf16raw* hc_leaf = Bfrag + 640 * 384;
    float* lossv6 = (float*)(hc_leaf + (size_t)NVOCAB * 256);
    float* bias_cat = lossv6 + (size_t)NVOCAB * 6;
    float* partials = bias_cat + 640;

    k_prep_embeds<<<(NVOCAB * 128 / 4 + 255) / 256, 256, 0, stream>>>(
        embeds, embeds_bf, NVOCAB * 128 / 4);
    k_prep_bcat<<<640, 128, 0, stream>>>(Wix, bix, Wih, bih, Wfx, bfx, Wfh, bfh,
                                         Wox, box_, Woh, boh, Wux, bux, Wuh, buh,
                                         Bfrag, bias_cat);
    hipMemsetAsync(partials, 0, 1024 * sizeof(float), stream);

    k_leafpre<<<(NVOCAB + 127) / 128, 256, 0, stream>>>(
        embeds_bf, Bfrag, bias_cat, Wout, bout, hc_leaf, lossv6, 0, NVOCAB);

    for (int l = DEPTH - 2; l >= 0; --l) {
        const int n = 1 << l;
        const int off = n - 1;
        k_level32<<<dim3((n + 31) / 32), 256, 0, stream>>>(
            embeds_bf, words, labels, h_all, c_all, hc_leaf, lossv6,
            Bfrag, bias_cat, Wout, bout, partials, out,
            off, n, (l == DEPTH - 2) ? 1 : 0, (l == 0) ? 1 : 0);
    }
    k3_reduce<<<1, 256, 0, stream>>>(partials, out);
}

// Round 6
// 427.714 us; speedup vs baseline: 1.4361x; 1.4361x over previous
//
#include <hip/hip_runtime.h>
#include <math.h>

#define DEPTH 18
#define NINT ((1 << (DEPTH - 1)) - 1)   // internal nodes (h/c stored)
#define NVOCAB 50000

typedef unsigned short bf16raw;
typedef __bf16 bf16x8 __attribute__((ext_vector_type(8)));
typedef float f32x4 __attribute__((ext_vector_type(4)));
typedef short short8 __attribute__((ext_vector_type(8)));

__device__ __forceinline__ float sigm(float x) { return 1.0f / (1.0f + __expf(-x)); }
// NaN-safe fast tanh: x->+inf => 1-0=1; x->-inf => 1-2=-1.  Replaces libm
// tanhf (~20-40 instrs) with ~5 (round-5 VALUBusy 25% was tanhf-dominated).
__device__ __forceinline__ float fast_tanh(float x) {
    float t = __expf(2.0f * x);
    return 1.0f - 2.0f / (t + 1.0f);
}

__device__ __forceinline__ float bf2f(bf16raw u) {
    union { unsigned int i; float f; } v;
    v.i = ((unsigned int)u) << 16;
    return v.f;
}
__device__ __forceinline__ bf16raw f2bf(float f) {
    union { float f; unsigned int i; } v;
    v.f = f;
    unsigned int r = v.i + 0x7FFFu + ((v.i >> 16) & 1u);  // RNE
    return (bf16raw)(r >> 16);
}

#define SB() __builtin_amdgcn_sched_barrier(0)

// ---------------------------------------------------------------------------
__global__ __launch_bounds__(256) void k_prep_embeds(const float* __restrict__ src,
                                                     bf16raw* __restrict__ dst, int n4)
{
    int i = blockIdx.x * blockDim.x + threadIdx.x;
    if (i < n4) {
        float4 v = ((const float4*)src)[i];
        ushort4 o;
        o.x = f2bf(v.x); o.y = f2bf(v.y); o.z = f2bf(v.z); o.w = f2bf(v.w);
        ((ushort4*)dst)[i] = o;
    }
}

// ---------------------------------------------------------------------------
// Bfrag: fragment-linear B.  Gate order: 0=i, 1=u, 2=o, 3=f1, 4=f2.
// Physical: Bfrag[((tile*12 + ktile)*64 + lane)*8 + e] where tile=col>>4,
// lane = ((k>>3)&3)*16 + (col&15), ktile=k>>5, e=k&7.  A wave loading one
// MFMA B fragment reads 64 consecutive 16B chunks -> one coalesced 1KB txn.
// f1 zero for k>=256, f2 zero for k in [128,256).
// ---------------------------------------------------------------------------
__global__ __launch_bounds__(128) void k_prep_bcat(
    const float* __restrict__ Wix, const float* __restrict__ bix,
    const float* __restrict__ Wih, const float* __restrict__ bih,
    const float* __restrict__ Wfx, const float* __restrict__ bfx,
    const float* __restrict__ Wfh, const float* __restrict__ bfh,
    const float* __restrict__ Wox, const float* __restrict__ box_,
    const float* __restrict__ Woh, const float* __restrict__ boh,
    const float* __restrict__ Wux, const float* __restrict__ bux,
    const float* __restrict__ Wuh, const float* __restrict__ buh,
    bf16raw* __restrict__ Bfrag, float* __restrict__ bias_cat)
{
    const int j = blockIdx.x;        // 0..639
    const int grp = j >> 7, jj = j & 127;
    const float *Wx, *Wh, *bx, *bh;
    switch (grp) {
        case 0: Wx = Wix; Wh = Wih; bx = bix;  bh = bih; break;
        case 1: Wx = Wux; Wh = Wuh; bx = bux;  bh = buh; break;
        case 2: Wx = Wox; Wh = Woh; bx = box_; bh = boh; break;
        default: Wx = Wfx; Wh = Wfh; bx = bfx; bh = bfh; break;
    }
    const int tile = j >> 4, lr = j & 15;
    for (int k = threadIdx.x; k < 384; k += blockDim.x) {
        float v;
        if (k < 128) {
            v = Wx[jj * 128 + k];
        } else if (k < 256) {
            v = (grp == 4) ? 0.f : Wh[jj * 128 + (k - 128)];
        } else {
            v = (grp == 3) ? 0.f : Wh[jj * 128 + (k - 256)];
        }
        const int idx = ((tile * 12 + (k >> 5)) * 64 + ((k >> 3) & 3) * 16 + lr) * 8 + (k & 7);
        Bfrag[idx] = f2bf(v);
    }
    if (threadIdx.x == 0) bias_cat[j] = bx[jj] + bh[jj];
}

// ---------------------------------------------------------------------------
// Pipelined fragment helpers (all indices compile-time -> stay in registers).
// ---------------------------------------------------------------------------
__device__ __forceinline__ constexpr unsigned chunk_mask(int kt) {
    return (kt < 4) ? 0x1Fu : (kt < 8 ? 0x0Fu : 0x17u);
}

template<int KT>
__device__ __forceinline__ void lv_load(const bf16raw* __restrict__ bfbase, int w,
                                        bf16x8 (&buf)[10])
{
    constexpr unsigned mask = chunk_mask(KT);
    int s = 0;
#pragma unroll
    for (int g = 0; g < 5; ++g) {
        if (!((mask >> g) & 1)) continue;
#pragma unroll
        for (int jj = 0; jj < 2; ++jj) {
            buf[s] = *(const bf16x8*)(bfbase + (long)(((g * 8 + w * 2 + jj) * 12 + KT) * 512));
            ++s;
        }
    }
}

template<int KT>
__device__ __forceinline__ void lv_aload(const bf16raw* __restrict__ sA, int lrow, int lquad,
                                         bf16x8 (&af)[2])
{
#pragma unroll
    for (int i = 0; i < 2; ++i)
        af[i] = *(const bf16x8*)&sA[(i * 16 + lrow) * 392 + KT * 32 + lquad * 8];
}

template<int KT>
__device__ __forceinline__ void lv_mfma(bf16x8 (&af)[2], bf16x8 (&buf)[10],
                                        f32x4 (&acc)[5][2][2])
{
    constexpr unsigned mask = chunk_mask(KT);
    int s = 0;
#pragma unroll
    for (int g = 0; g < 5; ++g) {
        if (!((mask >> g) & 1)) continue;
#pragma unroll
        for (int jj = 0; jj < 2; ++jj) {
#pragma unroll
            for (int i = 0; i < 2; ++i)
                acc[g][i][jj] = __builtin_amdgcn_mfma_f32_16x16x32_bf16(af[i], buf[s], acc[g][i][jj], 0, 0, 0);
            ++s;
        }
    }
}

template<int CB, int KT>
__device__ __forceinline__ void lp_load(const bf16raw* __restrict__ bfbase, int wcol,
                                        bf16x8 (&buf)[4])
{
#pragma unroll
    for (int j = 0; j < 4; ++j)
        buf[j] = *(const bf16x8*)(bfbase + (long)(((CB * 8 + (wcol >> 4) + j) * 12 + KT) * 512));
}

template<int KT>
__device__ __forceinline__ void lp_mfma(const bf16raw* __restrict__ sA, int wrow, int lrow,
                                        int lquad, bf16x8 (&buf)[4], f32x4 (&acc)[4][4])
{
    bf16x8 af[4];
#pragma unroll
    for (int i = 0; i < 4; ++i)
        af[i] = *(const bf16x8*)&sA[(wrow + i * 16 + lrow) * 136 + KT * 32 + lquad * 8];
#pragma unroll
    for (int i = 0; i < 4; ++i)
#pragma unroll
        for (int j = 0; j < 4; ++j)
            acc[i][j] = __builtin_amdgcn_mfma_f32_16x16x32_bf16(af[i], buf[j], acc[i][j], 0, 0, 0);
}

// B pipelined depth-2 (3 buffers), order pinned with sched_barrier(0) so the
// scheduler cannot sink the loads back to their uses (round-5 null: VGPR
// stayed 80 -> pipeline collapsed without fences).
template<int CB>
__device__ __forceinline__ void lp_rungemm(const bf16raw* __restrict__ sA,
                                           const bf16raw* __restrict__ bfbase,
                                           int wrow, int wcol, int lrow, int lquad,
                                           f32x4 (&acc)[4][4])
{
#pragma unroll
    for (int i = 0; i < 4; i++)
#pragma unroll
        for (int j = 0; j < 4; j++) acc[i][j] = (f32x4){0.f, 0.f, 0.f, 0.f};
    bf16x8 c0[4], c1[4], c2[4];
    lp_load<CB, 0>(bfbase, wcol, c0);
    lp_load<CB, 1>(bfbase, wcol, c1);
    SB();
    lp_load<CB, 2>(bfbase, wcol, c2);
    SB();
    lp_mfma<0>(sA, wrow, lrow, lquad, c0, acc);
    SB();
    lp_load<CB, 3>(bfbase, wcol, c0);
    SB();
    lp_mfma<1>(sA, wrow, lrow, lquad, c1, acc);
    SB();
    lp_mfma<2>(sA, wrow, lrow, lquad, c2, acc);
    lp_mfma<3>(sA, wrow, lrow, lquad, c0, acc);
}

// ---------------------------------------------------------------------------
// k_leafpre: per-vocab leaf tables. hc_leaf[v][0..127]=h, [128..255]=c;
// lossv6[v][0..4]=logits, [5]=lse.  A staged once in LDS; B via fenced
// depth-2 pipelined coalesced Bfrag loads; barrier-free K-loop.
// ---------------------------------------------------------------------------
__global__ __launch_bounds__(256, 2) void k_leafpre(
    const bf16raw* __restrict__ embeds_bf,
    const bf16raw* __restrict__ Bfrag, const float* __restrict__ bias_cat,
    const float* __restrict__ Wout, const float* __restrict__ bout,
    bf16raw* __restrict__ hc_leaf, float* __restrict__ lossv6, int vbase, int nv)
{
    vbase += blockIdx.x * 128;
    nv -= vbase;
    if (nv > 128) nv = 128;
    if (nv <= 0) return;

    __shared__ __align__(16) bf16raw sA[128 * 136];
    __shared__ __align__(16) bf16raw sT[128 * 136];
    __shared__ float sWout[5 * 128];

    const int t = threadIdx.x;
    for (int i = t; i < 640; i += 256) sWout[i] = Wout[i];

    // ---- stage full A tile once: 2 threads/row x 8 short8 ----
    {
        const int row = t >> 1;
        const int half = (t & 1) * 64;
        const int arow = (row < nv) ? row : 0;
        const bf16raw* ax = embeds_bf + (long)(vbase + arow) * 128;
#pragma unroll
        for (int s = 0; s < 8; ++s)
            *(short8*)&sA[row * 136 + half + s * 8] = *(const short8*)(ax + half + s * 8);
    }

    const int lane = t & 63;
    const int w = t >> 6;
    const int wrow = (w >> 1) * 64;
    const int wcol = (w & 1) * 64;
    const int lrow = lane & 15;
    const int lquad = lane >> 4;

    __syncthreads();

    const bf16raw* bfbase = Bfrag + (long)lane * 8;

    float tval[4][4][4];
    f32x4 acc[4][4];

    // ---- i gate ----
    lp_rungemm<0>(sA, bfbase, wrow, wcol, lrow, lquad, acc);
#pragma unroll
    for (int i = 0; i < 4; i++)
#pragma unroll
        for (int jj = 0; jj < 4; jj++) {
            const float b = bias_cat[wcol + jj * 16 + lrow];
#pragma unroll
            for (int r = 0; r < 4; r++) tval[i][jj][r] = sigm(acc[i][jj][r] + b);
        }
    // ---- u gate: tval = c = i*u ----
    lp_rungemm<1>(sA, bfbase, wrow, wcol, lrow, lquad, acc);
#pragma unroll
    for (int i = 0; i < 4; i++)
#pragma unroll
        for (int jj = 0; jj < 4; jj++) {
            const float b = bias_cat[128 + wcol + jj * 16 + lrow];
#pragma unroll
            for (int r = 0; r < 4; r++) tval[i][jj][r] *= fast_tanh(acc[i][jj][r] + b);
        }
    // write c tile, then keep tanh(c) in regs
#pragma unroll
    for (int i = 0; i < 4; i++)
#pragma unroll
        for (int jj = 0; jj < 4; jj++)
#pragma unroll
            for (int r = 0; r < 4; r++) {
                const int m = wrow + i * 16 + lquad * 4 + r;
                const int j = wcol + jj * 16 + lrow;
                sT[m * 136 + j] = f2bf(tval[i][jj][r]);
            }
#pragma unroll
    for (int i = 0; i < 4; i++)
#pragma unroll
        for (int jj = 0; jj < 4; jj++)
#pragma unroll
            for (int r = 0; r < 4; r++) tval[i][jj][r] = fast_tanh(tval[i][jj][r]);
    __syncthreads();
    // flush c to hc_leaf[.., 128..255]
#pragma unroll
    for (int s = 0; s < 8; ++s) {
        int ci = t + 256 * s;
        int row = ci >> 4, c8 = (ci & 15) * 8;
        if (row < nv)
            *(short8*)(hc_leaf + (long)(vbase + row) * 256 + 128 + c8) = *(const short8*)&sT[row * 136 + c8];
    }
    // ---- o gate: h = sigm(o) * tanh(c) ----
    lp_rungemm<2>(sA, bfbase, wrow, wcol, lrow, lquad, acc);
    __syncthreads();
#pragma unroll
    for (int i = 0; i < 4; i++)
#pragma unroll
        for (int jj = 0; jj < 4; jj++) {
            const float b = bias_cat[256 + wcol + jj * 16 + lrow];
#pragma unroll
            for (int r = 0; r < 4; r++) {
                const int m = wrow + i * 16 + lquad * 4 + r;
                const int j = wcol + jj * 16 + lrow;
                sT[m * 136 + j] = f2bf(sigm(acc[i][jj][r] + b) * tval[i][jj][r]);
            }
        }
    __syncthreads();
    // flush h to hc_leaf[.., 0..127]
#pragma unroll
    for (int s = 0; s < 8; ++s) {
        int ci = t + 256 * s;
        int row = ci >> 4, c8 = (ci & 15) * 8;
        if (row < nv)
            *(short8*)(hc_leaf + (long)(vbase + row) * 256 + c8) = *(const short8*)&sT[row * 136 + c8];
    }
    // logits + lse per vocab row
    {
        const int row = t >> 1, half = t & 1;
        float p[5] = {0.f, 0.f, 0.f, 0.f, 0.f};
        for (int k = 0; k < 64; ++k) {
            float hv = bf2f(sT[row * 136 + half * 64 + k]);
#pragma unroll
            for (int l = 0; l < 5; l++) p[l] += hv * sWout[l * 128 + half * 64 + k];
        }
#pragma unroll
        for (int l = 0; l < 5; l++) p[l] += __shfl_down(p[l], 1);
        if (half == 0 && row < nv) {
            float lg[5], mx = -1e30f;
#pragma unroll
            for (int l = 0; l < 5; l++) {
                lg[l] = p[l] + bout[l];
                mx = fmaxf(mx, lg[l]);
            }
            float se = 0.f;
#pragma unroll
            for (int l = 0; l < 5; l++) se += __expf(lg[l] - mx);
            float lse = __logf(se) + mx;
            float* dst = lossv6 + (long)(vbase + row) * 6;
#pragma unroll
            for (int l = 0; l < 5; l++) dst[l] = lg[l];
            dst[5] = lse;
        }
    }
}

// ---------------------------------------------------------------------------
// k_level32: fused level kernel (5-gate GEMM + gate math + h/c + loss).
//  - block = 32 nodes, 256 threads (4 waves).
//  - A tile staged once in LDS; children c staged in LDS; one barrier, then
//    the whole 5-gate K-loop is barrier-free.
//  - B via depth-2 3-buffer pipelined coalesced Bfrag loads + depth-1 A-LDS
//    prefetch, order PINNED with sched_barrier(0) after each load group and
//    each MFMA group (round-5 showed the scheduler otherwise collapses the
//    pipeline: VGPR stayed 80).  Compiler then emits counted vmcnt waits
//    with 2 chunks of loads in flight.
// ---------------------------------------------------------------------------
__global__ __launch_bounds__(256, 2) void k_level32(
    const bf16raw* __restrict__ embeds_bf, const int* __restrict__ words,
    const int* __restrict__ labels,
    bf16raw* __restrict__ h_all, bf16raw* __restrict__ c_all,
    const bf16raw* __restrict__ hc_leaf, const float* __restrict__ lossv6,
    const bf16raw* __restrict__ Bfrag, const float* __restrict__ bias_cat,
    const float* __restrict__ Wout, const float* __restrict__ bout,
    float* __restrict__ partials, float* __restrict__ out,
    int off, int nm, int leafkids, int isroot)
{
    __shared__ __align__(16) bf16raw sA[32 * 392];    // A tile, row stride 392
    __shared__ __align__(16) bf16raw sCT[64 * 136];   // children c; reused as c/h out tiles
    __shared__ float sWout[640];

    const int t = threadIdx.x;
    const int m0 = blockIdx.x * 32;

    for (int i = t; i < 640; i += 256) sWout[i] = Wout[i];

    // ---- stage A tile: 8 threads per row; each thread 6 short8 (full cover) ----
    {
        const int row = t >> 3;            // 0..31
        const int co = (t & 7) * 8;        // 0..56, 16B chunks
        int mm = m0 + row; if (mm >= nm) mm = nm - 1;
        const long g = (long)off + mm;
        const bf16raw* px = embeds_bf + (long)words[g] * 128;
        const bf16raw *p1, *p2;
        if (leafkids) {
            p1 = hc_leaf + (long)words[2 * g + 1] * 256;
            p2 = hc_leaf + (long)words[2 * g + 2] * 256;
        } else {
            p1 = h_all + (2 * g + 1) * 128;
            p2 = h_all + (2 * g + 2) * 128;
        }
        *(short8*)&sA[row * 392 + co]            = *(const short8*)(px + co);
        *(short8*)&sA[row * 392 + 64 + co]       = *(const short8*)(px + 64 + co);
        *(short8*)&sA[row * 392 + 128 + co]      = *(const short8*)(p1 + co);
        *(short8*)&sA[row * 392 + 192 + co]      = *(const short8*)(p1 + 64 + co);
        *(short8*)&sA[row * 392 + 256 + co]      = *(const short8*)(p2 + co);
        *(short8*)&sA[row * 392 + 320 + co]      = *(const short8*)(p2 + 64 + co);
    }
    // ---- stage children c: slot = 2*mlocal + childIdx; 4 thr/slot x 4 short8 ----
    {
        const int slot = t >> 2;           // 0..63
        const int cc = (t & 3) * 8;        // 0..24
        int mm = m0 + (slot >> 1); if (mm >= nm) mm = nm - 1;
        const long g = (long)off + mm;
        const long cg = 2 * g + 1 + (slot & 1);
        const bf16raw* pc = leafkids ? (hc_leaf + (long)words[cg] * 256 + 128)
                                     : (c_all + cg * 128);
#pragma unroll
        for (int s = 0; s < 4; ++s)
            *(short8*)&sCT[slot * 136 + s * 32 + cc] = *(const short8*)(pc + s * 32 + cc);
    }

    const int lane = t & 63;
    const int w = t >> 6;
    const int lrow = lane & 15;
    const int lquad = lane >> 4;

    __syncthreads();   // A tile, children, sWout staged

    // ---- 5-gate GEMM, barrier-free, fenced software pipeline ----
    f32x4 acc[5][2][2];
#pragma unroll
    for (int g = 0; g < 5; ++g)
#pragma unroll
        for (int i = 0; i < 2; ++i)
#pragma unroll
            for (int jj = 0; jj < 2; ++jj) acc[g][i][jj] = (f32x4){0.f, 0.f, 0.f, 0.f};

    const bf16raw* bfbase = Bfrag + (long)lane * 8;

    bf16x8 b0[10], b1[10], b2[10];
    bf16x8 aA[2], aB[2];

    lv_aload<0>(sA, lrow, lquad, aA);
    lv_load<0>(bfbase, w, b0);
    lv_load<1>(bfbase, w, b1);
    SB();
    lv_load<2>(bfbase, w, b2);  lv_aload<1>(sA, lrow, lquad, aB);  SB();
    lv_mfma<0>(aA, b0, acc);                                       SB();
    lv_load<3>(bfbase, w, b0);  lv_aload<2>(sA, lrow, lquad, aA);  SB();
    lv_mfma<1>(aB, b1, acc);                                       SB();
    lv_load<4>(bfbase, w, b1);  lv_aload<3>(sA, lrow, lquad, aB);  SB();
    lv_mfma<2>(aA, b2, acc);                                       SB();
    lv_load<5>(bfbase, w, b2);  lv_aload<4>(sA, lrow, lquad, aA);  SB();
    lv_mfma<3>(aB, b0, acc);                                       SB();
    lv_load<6>(bfbase, w, b0);  lv_aload<5>(sA, lrow, lquad, aB);  SB();
    lv_mfma<4>(aA, b1, acc);                                       SB();
    lv_load<7>(bfbase, w, b1);  lv_aload<6>(sA, lrow, lquad, aA);  SB();
    lv_mfma<5>(aB, b2, acc);                                       SB();
    lv_load<8>(bfbase, w, b2);  lv_aload<7>(sA, lrow, lquad, aB);  SB();
    lv_mfma<6>(aA, b0, acc);                                       SB();
    lv_load<9>(bfbase, w, b0);  lv_aload<8>(sA, lrow, lquad, aA);  SB();
    lv_mfma<7>(aB, b1, acc);                                       SB();
    lv_load<10>(bfbase, w, b1); lv_aload<9>(sA, lrow, lquad, aB);  SB();
    lv_mfma<8>(aA, b2, acc);                                       SB();
    lv_load<11>(bfbase, w, b2); lv_aload<10>(sA, lrow, lquad, aA); SB();
    lv_mfma<9>(aB, b0, acc);                                       SB();
    lv_aload<11>(sA, lrow, lquad, aB);                             SB();
    lv_mfma<10>(aA, b1, acc);
    lv_mfma<11>(aB, b2, acc);

    // ---- gate math fully in-register (reads children from sCT) ----
    float cv[2][2][4], hv[2][2][4];
#pragma unroll
    for (int i = 0; i < 2; ++i)
#pragma unroll
        for (int jj = 0; jj < 2; ++jj) {
            const int j = w * 32 + jj * 16 + lrow;
            const float bi = bias_cat[j];
            const float bu = bias_cat[128 + j];
            const float bo = bias_cat[256 + j];
            const float b1v = bias_cat[384 + j];
            const float b2v = bias_cat[512 + j];
#pragma unroll
            for (int r = 0; r < 4; ++r) {
                const int m = i * 16 + lquad * 4 + r;
                const float c1 = bf2f(sCT[(2 * m) * 136 + j]);
                const float c2 = bf2f(sCT[(2 * m + 1) * 136 + j]);
                const float iv = sigm(acc[0][i][jj][r] + bi);
                const float uv = fast_tanh(acc[1][i][jj][r] + bu);
                const float ov = sigm(acc[2][i][jj][r] + bo);
                const float f1 = sigm(acc[3][i][jj][r] + b1v);
                const float f2 = sigm(acc[4][i][jj][r] + b2v);
                const float c = iv * uv + f1 * c1 + f2 * c2;
                cv[i][jj][r] = c;
                hv[i][jj][r] = ov * fast_tanh(c);
            }
        }
    __syncthreads();   // all child reads complete before overwriting sCT

    // ---- write c (rows 0..31) and h (rows 32..63) tiles ----
#pragma unroll
    for (int i = 0; i < 2; ++i)
#pragma unroll
        for (int jj = 0; jj < 2; ++jj) {
            const int j = w * 32 + jj * 16 + lrow;
#pragma unroll
            for (int r = 0; r < 4; ++r) {
                const int m = i * 16 + lquad * 4 + r;
                sCT[m * 136 + j] = f2bf(cv[i][jj][r]);
                sCT[(32 + m) * 136 + j] = f2bf(hv[i][jj][r]);
            }
        }
    __syncthreads();

    // ---- coalesced flush: rows 0..31 -> c_all, rows 32..63 -> h_all ----
#pragma unroll
    for (int q = 0; q < 4; ++q) {
        int ci = t + 256 * q;               // 0..1023
        int row = ci >> 4;                  // 0..63
        int c8 = (ci & 15) * 8;
        int m = row & 31;
        if (m0 + m < nm) {
            bf16raw* dst = (row < 32) ? c_all : h_all;
            *(short8*)(dst + ((long)off + m0 + m) * 128 + c8) = *(const short8*)&sCT[row * 136 + c8];
        }
    }

    // ---- logits + loss: 8 threads per node ----
    {
        const int row = t >> 3, oct = t & 7;
        float p[5] = {0.f, 0.f, 0.f, 0.f, 0.f};
#pragma unroll
        for (int k0 = 0; k0 < 16; ++k0) {
            const int k = oct * 16 + k0;
            float hval = bf2f(sCT[(32 + row) * 136 + k]);
#pragma unroll
            for (int l = 0; l < 5; l++) p[l] += hval * sWout[l * 128 + k];
        }
#pragma unroll
        for (int l = 0; l < 5; l++) {
            p[l] += __shfl_down(p[l], 4);
            p[l] += __shfl_down(p[l], 2);
            p[l] += __shfl_down(p[l], 1);
        }
        if (oct == 0 && m0 + row < nm) {
            const long g = (long)off + m0 + row;
            float lg[5], mx = -1e30f;
#pragma unroll
            for (int l = 0; l < 5; l++) {
                lg[l] = p[l] + bout[l];
                mx = fmaxf(mx, lg[l]);
            }
            float se = 0.f;
#pragma unroll
            for (int l = 0; l < 5; l++) se += __expf(lg[l] - mx);
            float lse = __logf(se) + mx;
            float lossNode = lse - lg[labels[g]];
            if (leafkids) {
                const float* lv1 = lossv6 + (long)words[2 * g + 1] * 6;
                const float* lv2 = lossv6 + (long)words[2 * g + 2] * 6;
                lossNode += (lv1[5] - lv1[labels[2 * g + 1]])
                          + (lv2[5] - lv2[labels[2 * g + 2]]);
            }
            atomicAdd(&partials[(int)(g & 1023)], lossNode);
            if (isroot) {
#pragma unroll
                for (int l = 0; l < 5; l++) out[l] = lg[l] - lse;
            }
        }
    }
}

__global__ __launch_bounds__(256) void k3_reduce(const float* __restrict__ partials,
                                                 float* __restrict__ out)
{
    const int t = threadIdx.x;
    float s = 0.f;
    for (int i = t; i < 1024; i += 256) s += partials[i];
#pragma unroll
    for (int d = 32; d > 0; d >>= 1) s += __shfl_down(s, d);
    __shared__ float red[4];
    if ((t & 63) == 0) red[t >> 6] = s;
    __syncthreads();
    if (t == 0) out[5] = red[0] + red[1] + red[2] + red[3];
}

// ---------------------------------------------------------------------------
extern "C" void kernel_launch(void* const* d_in, const int* in_sizes, int n_in,
                              void* d_out, int out_size, void* d_ws, size_t ws_size,
                              hipStream_t stream)
{
    const float* embeds = (const float*)d_in[0];
    const int* words = (const int*)d_in[1];
    const int* labels = (const int*)d_in[2];
    const float* Wix = (const float*)d_in[5],  *bix  = (const float*)d_in[6];
    const float* Wih = (const float*)d_in[7],  *bih  = (const float*)d_in[8];
    const float* Wfx = (const float*)d_in[9],  *bfx  = (const float*)d_in[10];
    const float* Wfh = (const float*)d_in[11], *bfh  = (const float*)d_in[12];
    const float* Wox = (const float*)d_in[13], *box_ = (const float*)d_in[14];
    const float* Woh = (const float*)d_in[15], *boh  = (const float*)d_in[16];
    const float* Wux = (const float*)d_in[17], *bux  = (const float*)d_in[18];
    const float* Wuh = (const float*)d_in[19], *buh  = (const float*)d_in[20];
    const float* Wout = (const float*)d_in[21], *bout = (const float*)d_in[22];
    float* out = (float*)d_out;

    char* ws = (char*)d_ws;
    const size_t treeElems = (size_t)NINT * 128;
    bf16raw* h_all = (bf16raw*)ws;
    bf16raw* c_all = h_all + treeElems;
    bf16raw* embeds_bf = c_all + treeElems;
    bf16raw* Bfrag = embeds_bf + (size_t)NVOCAB * 128;
    bf16raw* hc_leaf = Bfrag + 640 * 384;
    float* lossv6 = (float*)(hc_leaf + (size_t)NVOCAB * 256);
    float* bias_cat = lossv6 + (size_t)NVOCAB * 6;
    float* partials = bias_cat + 640;

    k_prep_embeds<<<(NVOCAB * 128 / 4 + 255) / 256, 256, 0, stream>>>(
        embeds, embeds_bf, NVOCAB * 128 / 4);
    k_prep_bcat<<<640, 128, 0, stream>>>(Wix, bix, Wih, bih, Wfx, bfx, Wfh, bfh,
                                         Wox, box_, Woh, boh, Wux, bux, Wuh, buh,
                                         Bfrag, bias_cat);
    hipMemsetAsync(partials, 0, 1024 * sizeof(float), stream);

    k_leafpre<<<(NVOCAB + 127) / 128, 256, 0, stream>>>(
        embeds_bf, Bfrag, bias_cat, Wout, bout, hc_leaf, lossv6, 0, NVOCAB);

    for (int l = DEPTH - 2; l >= 0; --l) {
        const int n = 1 << l;
        const int off = n - 1;
        k_level32<<<dim3((n + 31) / 32), 256, 0, stream>>>(
            embeds_bf, words, labels, h_all, c_all, hc_leaf, lossv6,
            Bfrag, bias_cat, Wout, bout, partials, out,
            off, n, (l == DEPTH - 2) ? 1 : 0, (l == 0) ? 1 : 0);
    }
    k3_reduce<<<1, 256, 0, stream>>>(partials, out);
}

// Round 7
// 415.162 us; speedup vs baseline: 1.4795x; 1.0302x over previous
//
#include <hip/hip_runtime.h>
#include <math.h>

#define DEPTH 18
#define NINT ((1 << (DEPTH - 1)) - 1)   // internal nodes (h/c stored)
#define NVOCAB 50000
#define SAW 520                          // sA row stride (elems): [x|hs|h1|h2] + pad

typedef unsigned short bf16raw;
typedef __bf16 bf16x8 __attribute__((ext_vector_type(8)));
typedef float f32x4 __attribute__((ext_vector_type(4)));
typedef short short8 __attribute__((ext_vector_type(8)));

__device__ __forceinline__ float sigm(float x) { return 1.0f / (1.0f + __expf(-x)); }
// NaN-safe fast tanh (saturates correctly at +-inf).
__device__ __forceinline__ float fast_tanh(float x) {
    float t = __expf(2.0f * x);
    return 1.0f - 2.0f / (t + 1.0f);
}

__device__ __forceinline__ float bf2f(bf16raw u) {
    union { unsigned int i; float f; } v;
    v.i = ((unsigned int)u) << 16;
    return v.f;
}
__device__ __forceinline__ bf16raw f2bf(float f) {
    union { float f; unsigned int i; } v;
    v.f = f;
    unsigned int r = v.i + 0x7FFFu + ((v.i >> 16) & 1u);  // RNE
    return (bf16raw)(r >> 16);
}

#define SB() __builtin_amdgcn_sched_barrier(0)

// ---------------------------------------------------------------------------
__global__ __launch_bounds__(256) void k_prep_embeds(const float* __restrict__ src,
                                                     bf16raw* __restrict__ dst, int n4)
{
    int i = blockIdx.x * blockDim.x + threadIdx.x;
    if (i < n4) {
        float4 v = ((const float4*)src)[i];
        ushort4 o;
        o.x = f2bf(v.x); o.y = f2bf(v.y); o.z = f2bf(v.z); o.w = f2bf(v.w);
        ((ushort4*)dst)[i] = o;
    }
}

// ---------------------------------------------------------------------------
// Bfrag: fragment-linear B, DEDUPLICATED via hs = h1+h2 restructure.
// Gates: 0=i, 1=u, 2=o, 3=f.  Each gate is [Wx | Wh], K=256 (8 ktiles).
//   i,u,o multiply A=[x|hs]; f is used twice: f1 over A=[x|h1], f2 over
//   A=[x|h2] (B identical -> loaded once per wave).
// Physical: Bfrag[(((gate*8 + coltile)*8 + ktile)*64 + lane)*8 + e]
//   coltile = col>>4, lane = ((k>>3)&3)*16 + (col&15), ktile = k>>5, e = k&7.
// One wave B-fragment load = 64 consecutive 16B chunks = coalesced 1KB txn.
// Total 256KB (vs 416KB duplicated form).
// ---------------------------------------------------------------------------
__global__ __launch_bounds__(128) void k_prep_bcat(
    const float* __restrict__ Wix, const float* __restrict__ bix,
    const float* __restrict__ Wih, const float* __restrict__ bih,
    const float* __restrict__ Wfx, const float* __restrict__ bfx,
    const float* __restrict__ Wfh, const float* __restrict__ bfh,
    const float* __restrict__ Wox, const float* __restrict__ box_,
    const float* __restrict__ Woh, const float* __restrict__ boh,
    const float* __restrict__ Wux, const float* __restrict__ bux,
    const float* __restrict__ Wuh, const float* __restrict__ buh,
    bf16raw* __restrict__ Bfrag, float* __restrict__ bias_cat)
{
    const int j = blockIdx.x;        // 0..511 = gate*128 + col
    const int gate = j >> 7, jj = j & 127;
    const float *Wx, *Wh, *bx, *bh;
    switch (gate) {
        case 0: Wx = Wix; Wh = Wih; bx = bix;  bh = bih; break;
        case 1: Wx = Wux; Wh = Wuh; bx = bux;  bh = buh; break;
        case 2: Wx = Wox; Wh = Woh; bx = box_; bh = boh; break;
        default: Wx = Wfx; Wh = Wfh; bx = bfx; bh = bfh; break;
    }
    const int coltile = (j >> 4) & 7, lr = j & 15;
    for (int k = threadIdx.x; k < 256; k += blockDim.x) {
        float v = (k < 128) ? Wx[jj * 128 + k] : Wh[jj * 128 + (k - 128)];
        const int idx = (((gate * 8 + coltile) * 8 + (k >> 5)) * 64
                         + ((k >> 3) & 3) * 16 + lr) * 8 + (k & 7);
        Bfrag[idx] = f2bf(v);
    }
    if (threadIdx.x == 0) bias_cat[j] = bx[jj] + bh[jj];
}

// ---------------------------------------------------------------------------
// k_leafpre burst helpers: gate CB, ktiles 0..3 (x-part), 4 coltiles/wave.
// ---------------------------------------------------------------------------
template<int CB>
__device__ __forceinline__ void lp_burst(const bf16raw* __restrict__ bfbase, int wcol,
                                         bf16x8 (&bb)[16])
{
#pragma unroll
    for (int kt = 0; kt < 4; ++kt)
#pragma unroll
        for (int j = 0; j < 4; ++j)
            bb[kt * 4 + j] = *(const bf16x8*)(bfbase +
                    (long)(((CB * 8 + (wcol >> 4) + j) * 8 + kt) * 512));
}

__device__ __forceinline__ void lp_mfma_all(const bf16raw* __restrict__ sA, int wrow,
                                            int lrow, int lquad,
                                            bf16x8 (&bb)[16], f32x4 (&acc)[4][4])
{
#pragma unroll
    for (int kt = 0; kt < 4; ++kt) {
        bf16x8 af[4];
#pragma unroll
        for (int i = 0; i < 4; ++i)
            af[i] = *(const bf16x8*)&sA[(wrow + i * 16 + lrow) * 136 + kt * 32 + lquad * 8];
#pragma unroll
        for (int i = 0; i < 4; ++i)
#pragma unroll
            for (int j = 0; j < 4; ++j)
                acc[i][j] = __builtin_amdgcn_mfma_f32_16x16x32_bf16(af[i], bb[kt * 4 + j], acc[i][j], 0, 0, 0);
    }
}

template<int CB>
__device__ __forceinline__ void lp_rungemm(const bf16raw* __restrict__ sA,
                                           const bf16raw* __restrict__ bfbase,
                                           int wrow, int wcol, int lrow, int lquad,
                                           f32x4 (&acc)[4][4])
{
#pragma unroll
    for (int i = 0; i < 4; i++)
#pragma unroll
        for (int j = 0; j < 4; j++) acc[i][j] = (f32x4){0.f, 0.f, 0.f, 0.f};
    bf16x8 bb[16];
    lp_burst<CB>(bfbase, wcol, bb);    // 16 loads in flight (one latency exposure)
    SB();
    lp_mfma_all(sA, wrow, lrow, lquad, bb, acc);
}

// ---------------------------------------------------------------------------
// k_level32 burst helpers.  Wave w: coltiles w*2, w*2+1 (cols w*32..w*32+31).
// ---------------------------------------------------------------------------
template<int G>
__device__ __forceinline__ void lv_loadB(const bf16raw* __restrict__ bfbase, int w,
                                         bf16x8 (&bb)[16])
{
#pragma unroll
    for (int kt = 0; kt < 8; ++kt)
#pragma unroll
        for (int jj = 0; jj < 2; ++jj)
            bb[kt * 2 + jj] = *(const bf16x8*)(bfbase +
                    (long)(((G * 8 + w * 2 + jj) * 8 + kt) * 512));
}

// PASS 0..2: i,u,o over A=[x|hs] (A-ktiles 0..7).
// PASS 3: f1 over [x (A-kt 0..3) | h1 (A-kt 8..11)].
// PASS 4: f2 over [x (A-kt 0..3) | h2 (A-kt 12..15)].
template<int PASS>
__device__ __forceinline__ void lv_pass(const bf16raw* __restrict__ sA, int lrow, int lquad,
                                        bf16x8 (&bb)[16], f32x4 (&acc)[2][2])
{
#pragma unroll
    for (int kt = 0; kt < 8; ++kt) {
        const int ktA = (PASS < 3) ? kt : ((kt < 4) ? kt : (PASS == 3 ? kt + 4 : kt + 8));
        bf16x8 af[2];
#pragma unroll
        for (int i = 0; i < 2; ++i)
            af[i] = *(const bf16x8*)&sA[(i * 16 + lrow) * SAW + ktA * 32 + lquad * 8];
#pragma unroll
        for (int jj = 0; jj < 2; ++jj)
#pragma unroll
            for (int i = 0; i < 2; ++i)
                acc[i][jj] = __builtin_amdgcn_mfma_f32_16x16x32_bf16(af[i], bb[kt * 2 + jj], acc[i][jj], 0, 0, 0);
    }
}

// ---------------------------------------------------------------------------
// k_leafpre: per-vocab leaf tables. hc_leaf[v][0..127]=h, [128..255]=c;
// lossv6[v][0..4]=logits, [5]=lse.  A staged once in LDS; per-gate 16-frag
// B bursts (one latency exposure per gate); barrier-free K-loop.
// ---------------------------------------------------------------------------
__global__ __launch_bounds__(256, 2) void k_leafpre(
    const bf16raw* __restrict__ embeds_bf,
    const bf16raw* __restrict__ Bfrag, const float* __restrict__ bias_cat,
    const float* __restrict__ Wout, const float* __restrict__ bout,
    bf16raw* __restrict__ hc_leaf, float* __restrict__ lossv6, int vbase, int nv)
{
    vbase += blockIdx.x * 128;
    nv -= vbase;
    if (nv > 128) nv = 128;
    if (nv <= 0) return;

    __shared__ __align__(16) bf16raw sA[128 * 136];
    __shared__ __align__(16) bf16raw sT[128 * 136];
    __shared__ float sWout[5 * 128];

    const int t = threadIdx.x;
    for (int i = t; i < 640; i += 256) sWout[i] = Wout[i];

    // ---- stage full A tile once: 2 threads/row x 8 short8 ----
    {
        const int row = t >> 1;
        const int half = (t & 1) * 64;
        const int arow = (row < nv) ? row : 0;
        const bf16raw* ax = embeds_bf + (long)(vbase + arow) * 128;
#pragma unroll
        for (int s = 0; s < 8; ++s)
            *(short8*)&sA[row * 136 + half + s * 8] = *(const short8*)(ax + half + s * 8);
    }

    const int lane = t & 63;
    const int w = t >> 6;
    const int wrow = (w >> 1) * 64;
    const int wcol = (w & 1) * 64;
    const int lrow = lane & 15;
    const int lquad = lane >> 4;

    __syncthreads();

    const bf16raw* bfbase = Bfrag + (long)lane * 8;

    float tval[4][4][4];
    f32x4 acc[4][4];

    // ---- i gate ----
    lp_rungemm<0>(sA, bfbase, wrow, wcol, lrow, lquad, acc);
#pragma unroll
    for (int i = 0; i < 4; i++)
#pragma unroll
        for (int jj = 0; jj < 4; jj++) {
            const float b = bias_cat[wcol + jj * 16 + lrow];
#pragma unroll
            for (int r = 0; r < 4; r++) tval[i][jj][r] = sigm(acc[i][jj][r] + b);
        }
    // ---- u gate: tval = c = i*u ----
    lp_rungemm<1>(sA, bfbase, wrow, wcol, lrow, lquad, acc);
#pragma unroll
    for (int i = 0; i < 4; i++)
#pragma unroll
        for (int jj = 0; jj < 4; jj++) {
            const float b = bias_cat[128 + wcol + jj * 16 + lrow];
#pragma unroll
            for (int r = 0; r < 4; r++) tval[i][jj][r] *= fast_tanh(acc[i][jj][r] + b);
        }
    // write c tile, then keep tanh(c) in regs
#pragma unroll
    for (int i = 0; i < 4; i++)
#pragma unroll
        for (int jj = 0; jj < 4; jj++)
#pragma unroll
            for (int r = 0; r < 4; r++) {
                const int m = wrow + i * 16 + lquad * 4 + r;
                const int j = wcol + jj * 16 + lrow;
                sT[m * 136 + j] = f2bf(tval[i][jj][r]);
            }
#pragma unroll
    for (int i = 0; i < 4; i++)
#pragma unroll
        for (int jj = 0; jj < 4; jj++)
#pragma unroll
            for (int r = 0; r < 4; r++) tval[i][jj][r] = fast_tanh(tval[i][jj][r]);
    __syncthreads();
    // flush c to hc_leaf[.., 128..255]
#pragma unroll
    for (int s = 0; s < 8; ++s) {
        int ci = t + 256 * s;
        int row = ci >> 4, c8 = (ci & 15) * 8;
        if (row < nv)
            *(short8*)(hc_leaf + (long)(vbase + row) * 256 + 128 + c8) = *(const short8*)&sT[row * 136 + c8];
    }
    // ---- o gate: h = sigm(o) * tanh(c) ----
    lp_rungemm<2>(sA, bfbase, wrow, wcol, lrow, lquad, acc);
    __syncthreads();
#pragma unroll
    for (int i = 0; i < 4; i++)
#pragma unroll
        for (int jj = 0; jj < 4; jj++) {
            const float b = bias_cat[256 + wcol + jj * 16 + lrow];
#pragma unroll
            for (int r = 0; r < 4; r++) {
                const int m = wrow + i * 16 + lquad * 4 + r;
                const int j = wcol + jj * 16 + lrow;
                sT[m * 136 + j] = f2bf(sigm(acc[i][jj][r] + b) * tval[i][jj][r]);
            }
        }
    __syncthreads();
    // flush h to hc_leaf[.., 0..127]
#pragma unroll
    for (int s = 0; s < 8; ++s) {
        int ci = t + 256 * s;
        int row = ci >> 4, c8 = (ci & 15) * 8;
        if (row < nv)
            *(short8*)(hc_leaf + (long)(vbase + row) * 256 + c8) = *(const short8*)&sT[row * 136 + c8];
    }
    // logits + lse per vocab row
    {
        const int row = t >> 1, half = t & 1;
        float p[5] = {0.f, 0.f, 0.f, 0.f, 0.f};
        for (int k = 0; k < 64; ++k) {
            float hv = bf2f(sT[row * 136 + half * 64 + k]);
#pragma unroll
            for (int l = 0; l < 5; l++) p[l] += hv * sWout[l * 128 + half * 64 + k];
        }
#pragma unroll
        for (int l = 0; l < 5; l++) p[l] += __shfl_down(p[l], 1);
        if (half == 0 && row < nv) {
            float lg[5], mx = -1e30f;
#pragma unroll
            for (int l = 0; l < 5; l++) {
                lg[l] = p[l] + bout[l];
                mx = fmaxf(mx, lg[l]);
            }
            float se = 0.f;
#pragma unroll
            for (int l = 0; l < 5; l++) se += __expf(lg[l] - mx);
            float lse = __logf(se) + mx;
            float* dst = lossv6 + (long)(vbase + row) * 6;
#pragma unroll
            for (int l = 0; l < 5; l++) dst[l] = lg[l];
            dst[5] = lse;
        }
    }
}

// ---------------------------------------------------------------------------
// k_level32: fused level kernel (dedup 4-gate GEMM + gate math + h/c + loss).
//  - block = 32 nodes, 256 threads (4 waves).
//  - A = [x | hs=h1+h2 | h1 | h2] (K=512) staged once in LDS (hs computed
//    during staging); children c staged in LDS; one barrier, then the whole
//    GEMM is barrier-free.
//  - B deduplicated: i,u,o run over [x|hs] (Wh used once, not twice); f
//    B-matrix [Wfx|Wfh] loaded ONCE and used for both f1 (A=[x|h1]) and
//    f2 (A=[x|h2]).  208->160 MFMA, 416->256KB B per block.
//  - B via per-gate 16-fragment BURSTS, 2-buffer ping-pong across gates:
//    MLP ~16-32 in flight, one L2 latency exposure per gate instead of the
//    round-6 depth-2 pipeline's ~6.
// acc: 0=i 1=u 2=o 3=f1 4=f2; elem (i,jj)[r]: row m = i*16+lquad*4+r,
//      col j = w*32 + jj*16 + lrow.
// ---------------------------------------------------------------------------
__global__ __launch_bounds__(256, 2) void k_level32(
    const bf16raw* __restrict__ embeds_bf, const int* __restrict__ words,
    const int* __restrict__ labels,
    bf16raw* __restrict__ h_all, bf16raw* __restrict__ c_all,
    const bf16raw* __restrict__ hc_leaf, const float* __restrict__ lossv6,
    const bf16raw* __restrict__ Bfrag, const float* __restrict__ bias_cat,
    const float* __restrict__ Wout, const float* __restrict__ bout,
    float* __restrict__ partials, float* __restrict__ out,
    int off, int nm, int leafkids, int isroot)
{
    __shared__ __align__(16) bf16raw sA[32 * SAW];    // [x|hs|h1|h2]
    __shared__ __align__(16) bf16raw sCT[64 * 136];   // children c; reused as c/h out
    __shared__ float sWout[640];

    const int t = threadIdx.x;
    const int m0 = blockIdx.x * 32;

    for (int i = t; i < 640; i += 256) sWout[i] = Wout[i];

    // ---- stage A tile: 8 threads/row; x,h1,h2 loaded, hs computed ----
    {
        const int row = t >> 3;            // 0..31
        const int co = (t & 7) * 8;        // 0..56
        int mm = m0 + row; if (mm >= nm) mm = nm - 1;
        const long g = (long)off + mm;
        const bf16raw* px = embeds_bf + (long)words[g] * 128;
        const bf16raw *p1, *p2;
        if (leafkids) {
            p1 = hc_leaf + (long)words[2 * g + 1] * 256;
            p2 = hc_leaf + (long)words[2 * g + 2] * 256;
        } else {
            p1 = h_all + (2 * g + 1) * 128;
            p2 = h_all + (2 * g + 2) * 128;
        }
        short8 vx0 = *(const short8*)(px + co);
        short8 vx1 = *(const short8*)(px + 64 + co);
        short8 h10 = *(const short8*)(p1 + co);
        short8 h11 = *(const short8*)(p1 + 64 + co);
        short8 h20 = *(const short8*)(p2 + co);
        short8 h21 = *(const short8*)(p2 + 64 + co);
        short8 hs0, hs1;
#pragma unroll
        for (int e = 0; e < 8; ++e) {
            hs0[e] = (short)f2bf(bf2f((bf16raw)(unsigned short)h10[e]) +
                                 bf2f((bf16raw)(unsigned short)h20[e]));
            hs1[e] = (short)f2bf(bf2f((bf16raw)(unsigned short)h11[e]) +
                                 bf2f((bf16raw)(unsigned short)h21[e]));
        }
        *(short8*)&sA[row * SAW + co]        = vx0;
        *(short8*)&sA[row * SAW + 64 + co]   = vx1;
        *(short8*)&sA[row * SAW + 128 + co]  = hs0;
        *(short8*)&sA[row * SAW + 192 + co]  = hs1;
        *(short8*)&sA[row * SAW + 256 + co]  = h10;
        *(short8*)&sA[row * SAW + 320 + co]  = h11;
        *(short8*)&sA[row * SAW + 384 + co]  = h20;
        *(short8*)&sA[row * SAW + 448 + co]  = h21;
    }
    // ---- stage children c: slot = 2*mlocal + childIdx; 4 thr/slot ----
    {
        const int slot = t >> 2;           // 0..63
        const int cc = (t & 3) * 8;
        int mm = m0 + (slot >> 1); if (mm >= nm) mm = nm - 1;
        const long g = (long)off + mm;
        const long cg = 2 * g + 1 + (slot & 1);
        const bf16raw* pc = leafkids ? (hc_leaf + (long)words[cg] * 256 + 128)
                                     : (c_all + cg * 128);
#pragma unroll
        for (int s = 0; s < 4; ++s)
            *(short8*)&sCT[slot * 136 + s * 32 + cc] = *(const short8*)(pc + s * 32 + cc);
    }

    const int lane = t & 63;
    const int w = t >> 6;
    const int lrow = lane & 15;
    const int lquad = lane >> 4;

    __syncthreads();   // A tile, children, sWout staged

    // ---- 5-pass GEMM (4 B bursts), barrier-free ----
    f32x4 acc[5][2][2];
#pragma unroll
    for (int g = 0; g < 5; ++g)
#pragma unroll
        for (int i = 0; i < 2; ++i)
#pragma unroll
            for (int jj = 0; jj < 2; ++jj) acc[g][i][jj] = (f32x4){0.f, 0.f, 0.f, 0.f};

    const bf16raw* bfbase = Bfrag + (long)lane * 8;

    bf16x8 bbA[16], bbB[16];
    lv_loadB<0>(bfbase, w, bbA);  SB();
    lv_loadB<1>(bfbase, w, bbB);  SB();
    lv_pass<0>(sA, lrow, lquad, bbA, acc[0]);  SB();
    lv_loadB<2>(bfbase, w, bbA);  SB();
    lv_pass<1>(sA, lrow, lquad, bbB, acc[1]);  SB();
    lv_loadB<3>(bfbase, w, bbB);  SB();
    lv_pass<2>(sA, lrow, lquad, bbA, acc[2]);  SB();
    lv_pass<3>(sA, lrow, lquad, bbB, acc[3]);  SB();
    lv_pass<4>(sA, lrow, lquad, bbB, acc[4]);

    // ---- gate math fully in-register (reads children from sCT) ----
    float cv[2][2][4], hv[2][2][4];
#pragma unroll
    for (int i = 0; i < 2; ++i)
#pragma unroll
        for (int jj = 0; jj < 2; ++jj) {
            const int j = w * 32 + jj * 16 + lrow;
            const float bi = bias_cat[j];
            const float bu = bias_cat[128 + j];
            const float bo = bias_cat[256 + j];
            const float bf = bias_cat[384 + j];
#pragma unroll
            for (int r = 0; r < 4; ++r) {
                const int m = i * 16 + lquad * 4 + r;
                const float c1 = bf2f(sCT[(2 * m) * 136 + j]);
                const float c2 = bf2f(sCT[(2 * m + 1) * 136 + j]);
                const float iv = sigm(acc[0][i][jj][r] + bi);
                const float uv = fast_tanh(acc[1][i][jj][r] + bu);
                const float ov = sigm(acc[2][i][jj][r] + bo);
                const float f1 = sigm(acc[3][i][jj][r] + bf);
                const float f2 = sigm(acc[4][i][jj][r] + bf);
                const float c = iv * uv + f1 * c1 + f2 * c2;
                cv[i][jj][r] = c;
                hv[i][jj][r] = ov * fast_tanh(c);
            }
        }
    __syncthreads();   // all child reads complete before overwriting sCT

    // ---- write c (rows 0..31) and h (rows 32..63) tiles ----
#pragma unroll
    for (int i = 0; i < 2; ++i)
#pragma unroll
        for (int jj = 0; jj < 2; ++jj) {
            const int j = w * 32 + jj * 16 + lrow;
#pragma unroll
            for (int r = 0; r < 4; ++r) {
                const int m = i * 16 + lquad * 4 + r;
                sCT[m * 136 + j] = f2bf(cv[i][jj][r]);
                sCT[(32 + m) * 136 + j] = f2bf(hv[i][jj][r]);
            }
        }
    __syncthreads();

    // ---- coalesced flush: rows 0..31 -> c_all, rows 32..63 -> h_all ----
#pragma unroll
    for (int q = 0; q < 4; ++q) {
        int ci = t + 256 * q;               // 0..1023
        int row = ci >> 4;                  // 0..63
        int c8 = (ci & 15) * 8;
        int m = row & 31;
        if (m0 + m < nm) {
            bf16raw* dst = (row < 32) ? c_all : h_all;
            *(short8*)(dst + ((long)off + m0 + m) * 128 + c8) = *(const short8*)&sCT[row * 136 + c8];
        }
    }

    // ---- logits + loss: 8 threads per node ----
    {
        const int row = t >> 3, oct = t & 7;
        float p[5] = {0.f, 0.f, 0.f, 0.f, 0.f};
#pragma unroll
        for (int k0 = 0; k0 < 16; ++k0) {
            const int k = oct * 16 + k0;
            float hval = bf2f(sCT[(32 + row) * 136 + k]);
#pragma unroll
            for (int l = 0; l < 5; l++) p[l] += hval * sWout[l * 128 + k];
        }
#pragma unroll
        for (int l = 0; l < 5; l++) {
            p[l] += __shfl_down(p[l], 4);
            p[l] += __shfl_down(p[l], 2);
            p[l] += __shfl_down(p[l], 1);
        }
        if (oct == 0 && m0 + row < nm) {
            const long g = (long)off + m0 + row;
            float lg[5], mx = -1e30f;
#pragma unroll
            for (int l = 0; l < 5; l++) {
                lg[l] = p[l] + bout[l];
                mx = fmaxf(mx, lg[l]);
            }
            float se = 0.f;
#pragma unroll
            for (int l = 0; l < 5; l++) se += __expf(lg[l] - mx);
            float lse = __logf(se) + mx;
            float lossNode = lse - lg[labels[g]];
            if (leafkids) {
                const float* lv1 = lossv6 + (long)words[2 * g + 1] * 6;
                const float* lv2 = lossv6 + (long)words[2 * g + 2] * 6;
                lossNode += (lv1[5] - lv1[labels[2 * g + 1]])
                          + (lv2[5] - lv2[labels[2 * g + 2]]);
            }
            atomicAdd(&partials[(int)(g & 1023)], lossNode);
            if (isroot) {
#pragma unroll
                for (int l = 0; l < 5; l++) out[l] = lg[l] - lse;
            }
        }
    }
}

__global__ __launch_bounds__(256) void k3_reduce(const float* __restrict__ partials,
                                                 float* __restrict__ out)
{
    const int t = threadIdx.x;
    float s = 0.f;
    for (int i = t; i < 1024; i += 256) s += partials[i];
#pragma unroll
    for (int d = 32; d > 0; d >>= 1) s += __shfl_down(s, d);
    __shared__ float red[4];
    if ((t & 63) == 0) red[t >> 6] = s;
    __syncthreads();
    if (t == 0) out[5] = red[0] + red[1] + red[2] + red[3];
}

// ---------------------------------------------------------------------------
extern "C" void kernel_launch(void* const* d_in, const int* in_sizes, int n_in,
                              void* d_out, int out_size, void* d_ws, size_t ws_size,
                              hipStream_t stream)
{
    const float* embeds = (const float*)d_in[0];
    const int* words = (const int*)d_in[1];
    const int* labels = (const int*)d_in[2];
    const float* Wix = (const float*)d_in[5],  *bix  = (const float*)d_in[6];
    const float* Wih = (const float*)d_in[7],  *bih  = (const float*)d_in[8];
    const float* Wfx = (const float*)d_in[9],  *bfx  = (const float*)d_in[10];
    const float* Wfh = (const float*)d_in[11], *bfh  = (const float*)d_in[12];
    const float* Wox = (const float*)d_in[13], *box_ = (const float*)d_in[14];
    const float* Woh = (const float*)d_in[15], *boh  = (const float*)d_in[16];
    const float* Wux = (const float*)d_in[17], *bux  = (const float*)d_in[18];
    const float* Wuh = (const float*)d_in[19], *buh  = (const float*)d_in[20];
    const float* Wout = (const float*)d_in[21], *bout = (const float*)d_in[22];
    float* out = (float*)d_out;

    char* ws = (char*)d_ws;
    const size_t treeElems = (size_t)NINT * 128;
    bf16raw* h_all = (bf16raw*)ws;
    bf16raw* c_all = h_all + treeElems;
    bf16raw* embeds_bf = c_all + treeElems;
    bf16raw* Bfrag = embeds_bf + (size_t)NVOCAB * 128;
    bf16raw* hc_leaf = Bfrag + 4 * 8 * 8 * 512;          // 256KB dedup B
    float* lossv6 = (float*)(hc_leaf + (size_t)NVOCAB * 256);
    float* bias_cat = lossv6 + (size_t)NVOCAB * 6;
    float* partials = bias_cat + 512;

    k_prep_embeds<<<(NVOCAB * 128 / 4 + 255) / 256, 256, 0, stream>>>(
        embeds, embeds_bf, NVOCAB * 128 / 4);
    k_prep_bcat<<<512, 128, 0, stream>>>(Wix, bix, Wih, bih, Wfx, bfx, Wfh, bfh,
                                         Wox, box_, Woh, boh, Wux, bux, Wuh, buh,
                                         Bfrag, bias_cat);
    hipMemsetAsync(partials, 0, 1024 * sizeof(float), stream);

    k_leafpre<<<(NVOCAB + 127) / 128, 256, 0, stream>>>(
        embeds_bf, Bfrag, bias_cat, Wout, bout, hc_leaf, lossv6, 0, NVOCAB);

    for (int l = DEPTH - 2; l >= 0; --l) {
        const int n = 1 << l;
        const int off = n - 1;
        k_level32<<<dim3((n + 31) / 32), 256, 0, stream>>>(
            embeds_bf, words, labels, h_all, c_all, hc_leaf, lossv6,
            Bfrag, bias_cat, Wout, bout, partials, out,
            off, n, (l == DEPTH - 2) ? 1 : 0, (l == 0) ? 1 : 0);
    }
    k3_reduce<<<1, 256, 0, stream>>>(partials, out);
}